// Round 1
// baseline (2018.038 us; speedup 1.0000x reference)
//
#include <hip/hip_runtime.h>
#include <hip/hip_bf16.h>
#include <math.h>

// MHA forward, fp32 baseline (round 0: correctness + counter anchor).
// B=4, S=2048, D=1024, H=16, dk=64.
// ws layout (fp32): Qp[B,H,S,64] | Kp[B,H,S,64] | Vp[B,H,S,64] | AO[B,S,1024]
//  = 4 * 33.55 MB = 134 MB.

#define SEQ 2048
#define NH 16
#define DKH 64
#define DM 1024
#define NB 4

// ===== GEMM: C[M,N] = A[M,K] @ W[N,K]^T + bias;  M=8192, N=K=1024 =====
// LAYOUT 0: head-split output  out[((b*NH+h)*SEQ+s)*64 + d]
// LAYOUT 1: row-major output   out[m*1024 + n]
template <int LAYOUT>
__global__ __launch_bounds__(256) void gemm_bias(
    const float* __restrict__ A, const float* __restrict__ W,
    const float* __restrict__ bias, float* __restrict__ out)
{
    __shared__ float As[16][128];   // [k][m]
    __shared__ float Ws[16][128];   // [k][n]
    const int t = threadIdx.x;
    const int bm = blockIdx.x;      // 64
    const int bn = blockIdx.y;      // 8
    const int tm = (t >> 4) << 3;   // 0..120
    const int tn = (t & 15) << 3;   // 0..120
    const int arow = t >> 1;        // 0..127
    const int acol = (t & 1) << 3;  // 0 or 8

    const float* Ag = A + (size_t)(bm * 128 + arow) * 1024 + acol;
    const float* Wg = W + (size_t)(bn * 128 + arow) * 1024 + acol;

    float c[8][8];
    #pragma unroll
    for (int i = 0; i < 8; ++i)
        #pragma unroll
        for (int j = 0; j < 8; ++j) c[i][j] = 0.0f;

    for (int kk = 0; kk < 1024; kk += 16) {
        const float4 a0 = *reinterpret_cast<const float4*>(Ag + kk);
        const float4 a1 = *reinterpret_cast<const float4*>(Ag + kk + 4);
        const float4 w0 = *reinterpret_cast<const float4*>(Wg + kk);
        const float4 w1 = *reinterpret_cast<const float4*>(Wg + kk + 4);
        __syncthreads();  // previous compute done before overwrite
        As[acol + 0][arow] = a0.x; As[acol + 1][arow] = a0.y;
        As[acol + 2][arow] = a0.z; As[acol + 3][arow] = a0.w;
        As[acol + 4][arow] = a1.x; As[acol + 5][arow] = a1.y;
        As[acol + 6][arow] = a1.z; As[acol + 7][arow] = a1.w;
        Ws[acol + 0][arow] = w0.x; Ws[acol + 1][arow] = w0.y;
        Ws[acol + 2][arow] = w0.z; Ws[acol + 3][arow] = w0.w;
        Ws[acol + 4][arow] = w1.x; Ws[acol + 5][arow] = w1.y;
        Ws[acol + 6][arow] = w1.z; Ws[acol + 7][arow] = w1.w;
        __syncthreads();
        #pragma unroll
        for (int k = 0; k < 16; ++k) {
            const float4 x0 = *reinterpret_cast<const float4*>(&As[k][tm]);
            const float4 x1 = *reinterpret_cast<const float4*>(&As[k][tm + 4]);
            const float4 y0 = *reinterpret_cast<const float4*>(&Ws[k][tn]);
            const float4 y1 = *reinterpret_cast<const float4*>(&Ws[k][tn + 4]);
            const float a_[8] = {x0.x, x0.y, x0.z, x0.w, x1.x, x1.y, x1.z, x1.w};
            const float b_[8] = {y0.x, y0.y, y0.z, y0.w, y1.x, y1.y, y1.z, y1.w};
            #pragma unroll
            for (int i = 0; i < 8; ++i)
                #pragma unroll
                for (int j = 0; j < 8; ++j)
                    c[i][j] = fmaf(a_[i], b_[j], c[i][j]);
        }
    }

    const int gn = bn * 128 + tn;
    #pragma unroll
    for (int i = 0; i < 8; ++i) {
        const int m = bm * 128 + tm + i;
        float r[8];
        #pragma unroll
        for (int j = 0; j < 8; ++j) r[j] = c[i][j] + bias[gn + j];
        float* op;
        if (LAYOUT == 0) {
            const int b = m >> 11, s = m & 2047;
            const int h = gn >> 6, d0 = gn & 63;  // gn%64 <= 56, 8-chunk stays in head
            op = out + (((size_t)(b * NH + h) * SEQ + s) * DKH + d0);
        } else {
            op = out + (size_t)m * 1024 + gn;
        }
        *reinterpret_cast<float4*>(op)     = make_float4(r[0], r[1], r[2], r[3]);
        *reinterpret_cast<float4*>(op + 4) = make_float4(r[4], r[5], r[6], r[7]);
    }
}

// ===== Flash attention (fp32): per block one (b,h) and 64 q-rows =====
// grid (S/64=32, B*H=64), 256 threads. Online softmax, 64-key tiles.
__global__ __launch_bounds__(256) void attn_fwd(
    const float* __restrict__ Qp, const float* __restrict__ Kp,
    const float* __restrict__ Vp, float* __restrict__ AO)
{
    __shared__ float Qs[64][68];   // [dk][q]   (transposed)
    __shared__ float KVs[64][68];  // K phase: [dk][key]; V phase: [key][d]
    __shared__ float Ps[64][68];   // [key][q]  (transposed)

    const int t = threadIdx.x;
    const int qt = blockIdx.x;      // 0..31
    const int bh = blockIdx.y;      // 0..63
    const int tm = (t >> 4) << 2;   // q rows 0..60
    const int tn = (t & 15) << 2;   // cols 0..60
    const int lrow = t >> 2;        // staging row 0..63
    const int lcol = (t & 3) << 4;  // 0,16,32,48

    const size_t base = (size_t)bh * SEQ * DKH;

    {   // stage Q transposed (once)
        const float* Qg = Qp + base + (size_t)(qt * 64 + lrow) * DKH + lcol;
        #pragma unroll
        for (int i = 0; i < 4; ++i) {
            const float4 v4 = *reinterpret_cast<const float4*>(Qg + 4 * i);
            Qs[lcol + 4 * i + 0][lrow] = v4.x;
            Qs[lcol + 4 * i + 1][lrow] = v4.y;
            Qs[lcol + 4 * i + 2][lrow] = v4.z;
            Qs[lcol + 4 * i + 3][lrow] = v4.w;
        }
    }

    float run_m[4], l[4], o[4][4];
    #pragma unroll
    for (int i = 0; i < 4; ++i) {
        run_m[i] = -INFINITY; l[i] = 0.0f;
        #pragma unroll
        for (int j = 0; j < 4; ++j) o[i][j] = 0.0f;
    }

    for (int kt = 0; kt < SEQ / 64; ++kt) {
        const float* Kg = Kp + base + (size_t)(kt * 64 + lrow) * DKH + lcol;
        __syncthreads();  // prev PV done (also makes Qs visible on iter 0)
        #pragma unroll
        for (int i = 0; i < 4; ++i) {  // K transposed: KVs[dk][key]
            const float4 v4 = *reinterpret_cast<const float4*>(Kg + 4 * i);
            KVs[lcol + 4 * i + 0][lrow] = v4.x;
            KVs[lcol + 4 * i + 1][lrow] = v4.y;
            KVs[lcol + 4 * i + 2][lrow] = v4.z;
            KVs[lcol + 4 * i + 3][lrow] = v4.w;
        }
        __syncthreads();

        float sc[4][4];
        #pragma unroll
        for (int i = 0; i < 4; ++i)
            #pragma unroll
            for (int j = 0; j < 4; ++j) sc[i][j] = 0.0f;
        #pragma unroll 16
        for (int dk = 0; dk < 64; ++dk) {
            const float4 qa = *reinterpret_cast<const float4*>(&Qs[dk][tm]);
            const float4 kb = *reinterpret_cast<const float4*>(&KVs[dk][tn]);
            const float aa[4] = {qa.x, qa.y, qa.z, qa.w};
            const float bb[4] = {kb.x, kb.y, kb.z, kb.w};
            #pragma unroll
            for (int i = 0; i < 4; ++i)
                #pragma unroll
                for (int j = 0; j < 4; ++j)
                    sc[i][j] = fmaf(aa[i], bb[j], sc[i][j]);
        }

        // online softmax over this 64-key tile (row groups = 16 consecutive lanes)
        const float scl = 0.125f;  // 1/sqrt(64)
        #pragma unroll
        for (int i = 0; i < 4; ++i) {
            const float s0 = sc[i][0] * scl, s1 = sc[i][1] * scl;
            const float s2 = sc[i][2] * scl, s3 = sc[i][3] * scl;
            float mx = fmaxf(fmaxf(s0, s1), fmaxf(s2, s3));
            #pragma unroll
            for (int d = 1; d < 16; d <<= 1) mx = fmaxf(mx, __shfl_xor(mx, d, 64));
            const float nm = fmaxf(run_m[i], mx);
            const float esc = __expf(run_m[i] - nm);  // first iter: exp(-inf)=0
            run_m[i] = nm;
            const float p0 = __expf(s0 - nm), p1 = __expf(s1 - nm);
            const float p2 = __expf(s2 - nm), p3 = __expf(s3 - nm);
            float ssum = p0 + p1 + p2 + p3;
            #pragma unroll
            for (int d = 1; d < 16; d <<= 1) ssum += __shfl_xor(ssum, d, 64);
            l[i] = l[i] * esc + ssum;
            o[i][0] *= esc; o[i][1] *= esc; o[i][2] *= esc; o[i][3] *= esc;
            Ps[tn + 0][tm + i] = p0; Ps[tn + 1][tm + i] = p1;
            Ps[tn + 2][tm + i] = p2; Ps[tn + 3][tm + i] = p3;
        }
        __syncthreads();  // K consumed, P visible

        {   // stage V natural: KVs[key][d]
            const float* Vg = Vp + base + (size_t)(kt * 64 + lrow) * DKH + lcol;
            #pragma unroll
            for (int i = 0; i < 4; ++i) {
                const float4 v4 = *reinterpret_cast<const float4*>(Vg + 4 * i);
                *reinterpret_cast<float4*>(&KVs[lrow][lcol + 4 * i]) = v4;
            }
        }
        __syncthreads();

        #pragma unroll 16
        for (int ky = 0; ky < 64; ++ky) {
            const float4 pa = *reinterpret_cast<const float4*>(&Ps[ky][tm]);
            const float4 vb = *reinterpret_cast<const float4*>(&KVs[ky][tn]);
            const float aa[4] = {pa.x, pa.y, pa.z, pa.w};
            const float bb[4] = {vb.x, vb.y, vb.z, vb.w};
            #pragma unroll
            for (int i = 0; i < 4; ++i)
                #pragma unroll
                for (int j = 0; j < 4; ++j)
                    o[i][j] = fmaf(aa[i], bb[j], o[i][j]);
        }
    }

    // write AO[b][s][h*64+d]
    const int b = bh >> 4, h = bh & 15;
    #pragma unroll
    for (int i = 0; i < 4; ++i) {
        const int s = qt * 64 + tm + i;
        const float inv = 1.0f / l[i];
        float4 r = make_float4(o[i][0] * inv, o[i][1] * inv,
                               o[i][2] * inv, o[i][3] * inv);
        *reinterpret_cast<float4*>(AO + ((size_t)(b * SEQ + s) * DM) + h * DKH + tn) = r;
    }
}

extern "C" void kernel_launch(void* const* d_in, const int* in_sizes, int n_in,
                              void* d_out, int out_size, void* d_ws, size_t ws_size,
                              hipStream_t stream)
{
    const float* q  = (const float*)d_in[0];
    const float* k  = (const float*)d_in[1];
    const float* v  = (const float*)d_in[2];
    const float* Wq = (const float*)d_in[3];
    const float* bq = (const float*)d_in[4];
    const float* Wk = (const float*)d_in[5];
    const float* bk = (const float*)d_in[6];
    const float* Wv = (const float*)d_in[7];
    const float* bv = (const float*)d_in[8];
    const float* Wo = (const float*)d_in[9];
    const float* bo = (const float*)d_in[10];
    float* out = (float*)d_out;

    const size_t per = (size_t)NB * NH * SEQ * DKH;  // 8,388,608 floats
    float* ws = (float*)d_ws;
    float* Qp = ws;
    float* Kp = Qp + per;
    float* Vp = Kp + per;
    float* AO = Vp + per;

    dim3 gg(64, 8);
    gemm_bias<0><<<gg, 256, 0, stream>>>(q, Wq, bq, Qp);
    gemm_bias<0><<<gg, 256, 0, stream>>>(k, Wk, bk, Kp);
    gemm_bias<0><<<gg, 256, 0, stream>>>(v, Wv, bv, Vp);
    attn_fwd<<<dim3(32, 64), 256, 0, stream>>>(Qp, Kp, Vp, AO);
    gemm_bias<1><<<gg, 256, 0, stream>>>(AO, Wo, bo, out);
}

// Round 2
// 474.181 us; speedup vs baseline: 4.2558x; 4.2558x over previous
//
#include <hip/hip_runtime.h>
#include <hip/hip_bf16.h>
#include <math.h>

// MHA forward, bf16-MFMA rewrite (round 2).
// B=4, S=2048, D=1024, H=16, dk=64.

#define SEQ 2048
#define NH 16
#define DKH 64
#define DM 1024
#define NB 4

typedef float f32x4 __attribute__((ext_vector_type(4)));
typedef __bf16 bf16x8 __attribute__((ext_vector_type(8)));

#define GLOAD16(g, l)                                                          \
    __builtin_amdgcn_global_load_lds(                                          \
        (const __attribute__((address_space(1))) void*)(g),                    \
        (__attribute__((address_space(3))) void*)(l), 16, 0, 0)

// swizzles: byte-column XOR within a row, involution, 16B granular.
__device__ __forceinline__ int sw128(int row, int bc) { return bc ^ ((row & 7) << 4); }
__device__ __forceinline__ int sw64(int row, int bc)  { return bc ^ (((row >> 1) & 3) << 4); }

// ===== fp32 -> bf16 conversion =====
__global__ __launch_bounds__(256) void cvt_qkv(
    const float* __restrict__ q, const float* __restrict__ k, const float* __restrict__ v,
    __bf16* __restrict__ qb, __bf16* __restrict__ kb, __bf16* __restrict__ vb)
{
    const float* src = blockIdx.y == 0 ? q : (blockIdx.y == 1 ? k : v);
    __bf16* dst      = blockIdx.y == 0 ? qb : (blockIdx.y == 1 ? kb : vb);
    const size_t i = ((size_t)blockIdx.x * 256 + threadIdx.x) * 8;
    const float4 a = *reinterpret_cast<const float4*>(src + i);
    const float4 b = *reinterpret_cast<const float4*>(src + i + 4);
    bf16x8 o;
    o[0] = (__bf16)a.x; o[1] = (__bf16)a.y; o[2] = (__bf16)a.z; o[3] = (__bf16)a.w;
    o[4] = (__bf16)b.x; o[5] = (__bf16)b.y; o[6] = (__bf16)b.z; o[7] = (__bf16)b.w;
    *reinterpret_cast<bf16x8*>(dst + i) = o;
}

__global__ __launch_bounds__(256) void cvt_w(
    const float* __restrict__ wq, const float* __restrict__ wk,
    const float* __restrict__ wv, const float* __restrict__ wo,
    __bf16* __restrict__ oq, __bf16* __restrict__ ok,
    __bf16* __restrict__ ov, __bf16* __restrict__ oo)
{
    const int y = blockIdx.y;
    const float* src = y == 0 ? wq : (y == 1 ? wk : (y == 2 ? wv : wo));
    __bf16* dst      = y == 0 ? oq : (y == 1 ? ok : (y == 2 ? ov : oo));
    const float scale = (y == 0) ? 0.125f : 1.0f;  // fold 1/sqrt(dk) into Wq
    const size_t i = ((size_t)blockIdx.x * 256 + threadIdx.x) * 8;
    const float4 a = *reinterpret_cast<const float4*>(src + i);
    const float4 b = *reinterpret_cast<const float4*>(src + i + 4);
    bf16x8 o;
    o[0] = (__bf16)(a.x * scale); o[1] = (__bf16)(a.y * scale);
    o[2] = (__bf16)(a.z * scale); o[3] = (__bf16)(a.w * scale);
    o[4] = (__bf16)(b.x * scale); o[5] = (__bf16)(b.y * scale);
    o[6] = (__bf16)(b.z * scale); o[7] = (__bf16)(b.w * scale);
    *reinterpret_cast<bf16x8*>(dst + i) = o;
}

// ===== bf16 MFMA GEMM: C[M,N] = A[M,K] @ W[N,K]^T + bias*bscale =====
// M=8192, N=K=1024. 128x128 tile, BK=32, 4 waves (2x2 of 64x64 quadrants).
// LAYOUT 0: bf16 head-split out[((b*16+h)*2048+s)*64+d]; LAYOUT 1: fp32 out[m*1024+n]
template <int LAYOUT>
__global__ __launch_bounds__(256) void gemm_bf16(
    const __bf16* __restrict__ A, const __bf16* __restrict__ W,
    const float* __restrict__ bias, float bscale, void* __restrict__ outv)
{
    __shared__ __align__(16) char As[8192];  // [128 rows][32 bf16], swizzled
    __shared__ __align__(16) char Ws[8192];
    const int t = threadIdx.x;
    const int w = t >> 6, lane = t & 63, g = lane >> 4, ln = lane & 15;
    const int bm = blockIdx.x, bn = blockIdx.y;
    const int wr = w >> 1, wc = w & 1;

    // staging: thread t stages 16B at LDS linear t*16 (round0) / 4096+t*16 (round1)
    const int srow = t >> 2;             // 0..63
    const int sbc  = (t & 3) << 4;       // 0..48
    const int so   = sw64(srow, sbc);    // same value for row and row+64

    const char* Ag0 = (const char*)(A + (size_t)(bm * 128 + srow) * 1024) + so;
    const char* Ag1 = (const char*)(A + (size_t)(bm * 128 + 64 + srow) * 1024) + so;
    const char* Wg0 = (const char*)(W + (size_t)(bn * 128 + srow) * 1024) + so;
    const char* Wg1 = (const char*)(W + (size_t)(bn * 128 + 64 + srow) * 1024) + so;

    f32x4 acc[4][4];
    #pragma unroll
    for (int i = 0; i < 4; ++i)
        #pragma unroll
        for (int j = 0; j < 4; ++j)
            #pragma unroll
            for (int e = 0; e < 4; ++e) acc[i][j][e] = 0.0f;

    for (int kk = 0; kk < 1024; kk += 32) {
        __syncthreads();
        GLOAD16(Ag0 + kk * 2, As + t * 16);
        GLOAD16(Ag1 + kk * 2, As + 4096 + t * 16);
        GLOAD16(Wg0 + kk * 2, Ws + t * 16);
        GLOAD16(Wg1 + kk * 2, Ws + 4096 + t * 16);
        __syncthreads();

        bf16x8 a[4], b[4];
        #pragma unroll
        for (int mi = 0; mi < 4; ++mi) {
            const int row = wr * 64 + mi * 16 + ln;
            a[mi] = *reinterpret_cast<const bf16x8*>(As + row * 64 + sw64(row, g << 4));
        }
        #pragma unroll
        for (int ni = 0; ni < 4; ++ni) {
            const int row = wc * 64 + ni * 16 + ln;
            b[ni] = *reinterpret_cast<const bf16x8*>(Ws + row * 64 + sw64(row, g << 4));
        }
        #pragma unroll
        for (int mi = 0; mi < 4; ++mi)
            #pragma unroll
            for (int ni = 0; ni < 4; ++ni)
                acc[mi][ni] = __builtin_amdgcn_mfma_f32_16x16x32_bf16(
                    a[mi], b[ni], acc[mi][ni], 0, 0, 0);
    }

    const int gm0 = bm * 128 + wr * 64, gn0 = bn * 128 + wc * 64;
    #pragma unroll
    for (int mi = 0; mi < 4; ++mi)
        #pragma unroll
        for (int ni = 0; ni < 4; ++ni) {
            const int col = gn0 + ni * 16 + ln;
            const float bs = bias[col] * bscale;
            #pragma unroll
            for (int r = 0; r < 4; ++r) {
                const int row = gm0 + mi * 16 + g * 4 + r;
                const float val = acc[mi][ni][r] + bs;
                if (LAYOUT == 0) {
                    const int bb = row >> 11, s = row & 2047;
                    const int h = col >> 6, d = col & 63;
                    ((__bf16*)outv)[(((size_t)(bb * NH + h) * SEQ) + s) * DKH + d] = (__bf16)val;
                } else {
                    ((float*)outv)[(size_t)row * DM + col] = val;
                }
            }
        }
}

// ===== V transpose: Vp[bh][s][d] -> Vt[bh][d][s] (bf16) =====
__global__ __launch_bounds__(256) void transpose_v(
    const __bf16* __restrict__ Vp, __bf16* __restrict__ Vt)
{
    __shared__ __bf16 T[64][65];
    const int t = threadIdx.x, st = blockIdx.x, bh = blockIdx.y;
    const __bf16* src = Vp + ((size_t)bh * SEQ + st * 64) * DKH;
    #pragma unroll
    for (int r = 0; r < 2; ++r) {
        const int idx = r * 256 + t;
        const int s_l = idx >> 3, c8 = (idx & 7) << 3;
        const bf16x8 v8 = *reinterpret_cast<const bf16x8*>(src + s_l * DKH + c8);
        #pragma unroll
        for (int j = 0; j < 8; ++j) T[s_l][c8 + j] = v8[j];
    }
    __syncthreads();
    __bf16* dst = Vt + ((size_t)bh * DKH) * SEQ + st * 64;
    #pragma unroll
    for (int r = 0; r < 2; ++r) {
        const int idx = r * 256 + t;
        const int d = idx >> 3, s8 = (idx & 7) << 3;
        bf16x8 o;
        #pragma unroll
        for (int j = 0; j < 8; ++j) o[j] = T[s8 + j][d];
        *reinterpret_cast<bf16x8*>(dst + (size_t)d * SEQ + s8) = o;
    }
}

// ===== Flash attention, bf16 MFMA =====
// grid (S/64=32, B*H=64), 256 thr = 4 waves; wave w owns q rows [w*16, w*16+16).
// K/V^T staged via swizzled global_load_lds; Q in regs; P via wave-private LDS.
__global__ __launch_bounds__(256) void attn_mfma(
    const __bf16* __restrict__ Qp, const __bf16* __restrict__ Kp,
    const __bf16* __restrict__ Vt, __bf16* __restrict__ AO)
{
    __shared__ __align__(16) char Ks[8192];  // [64 key][64 dk] swizzled
    __shared__ __align__(16) char Vs[8192];  // [64 d][64 key] swizzled
    __shared__ __align__(16) char Ps[8192];  // 4 waves x [16 q][64 key] swizzled
    const int t = threadIdx.x;
    const int w = t >> 6, lane = t & 63, g = lane >> 4, ln = lane & 15;
    const int qt = blockIdx.x, bh = blockIdx.y;

    // Q fragments in registers (row = l&15 of this wave's 16-row strip)
    const __bf16* Qrow = Qp + ((size_t)bh * SEQ + qt * 64 + w * 16 + ln) * DKH;
    bf16x8 qf[2];
    qf[0] = *reinterpret_cast<const bf16x8*>(Qrow + g * 8);
    qf[1] = *reinterpret_cast<const bf16x8*>(Qrow + 32 + g * 8);

    // staging coords: thread t -> LDS linear t*16 (+4096 round1); tile row = t>>3 (+32)
    const int srow = t >> 3;            // 0..31
    const int sbc  = (t & 7) << 4;      // 0..112
    const int sK   = sw128(srow, sbc);  // same for srow and srow+32
    const char* Kg = (const char*)Kp + ((size_t)bh * SEQ + srow) * 128 + sK;
    const char* Vg = (const char*)Vt + ((size_t)bh * DKH + srow) * (SEQ * 2) + sK;

    f32x4 oacc[4];
    float mrun[4], lrun[4];
    #pragma unroll
    for (int i = 0; i < 4; ++i) {
        mrun[i] = -INFINITY; lrun[i] = 0.0f;
        #pragma unroll
        for (int e = 0; e < 4; ++e) oacc[i][e] = 0.0f;
    }
    char* PsW = Ps + w * 2048;

    for (int kt = 0; kt < 32; ++kt) {
        __syncthreads();
        GLOAD16(Kg + kt * 8192,              Ks + t * 16);
        GLOAD16(Kg + kt * 8192 + 32 * 128,   Ks + 4096 + t * 16);
        GLOAD16(Vg + kt * 128,               Vs + t * 16);
        GLOAD16(Vg + kt * 128 + 32 * (SEQ * 2), Vs + 4096 + t * 16);
        __syncthreads();

        // QK^T: sc[f] covers keys [f*16, f*16+16)
        f32x4 sc[4];
        #pragma unroll
        for (int f = 0; f < 4; ++f)
            #pragma unroll
            for (int e = 0; e < 4; ++e) sc[f][e] = 0.0f;
        #pragma unroll
        for (int ks = 0; ks < 2; ++ks)
            #pragma unroll
            for (int f = 0; f < 4; ++f) {
                const int kr = f * 16 + ln;
                const bf16x8 kb_ = *reinterpret_cast<const bf16x8*>(
                    Ks + kr * 128 + sw128(kr, ks * 64 + (g << 4)));
                sc[f] = __builtin_amdgcn_mfma_f32_16x16x32_bf16(qf[ks], kb_, sc[f], 0, 0, 0);
            }

        // online softmax; lane's q-row for reg r: q = g*4+r (wave-local)
        #pragma unroll
        for (int r = 0; r < 4; ++r) {
            float mx = fmaxf(fmaxf(sc[0][r], sc[1][r]), fmaxf(sc[2][r], sc[3][r]));
            #pragma unroll
            for (int d = 1; d < 16; d <<= 1) mx = fmaxf(mx, __shfl_xor(mx, d, 64));
            const float nm  = fmaxf(mrun[r], mx);
            const float esc = __expf(mrun[r] - nm);
            mrun[r] = nm;
            const float p0 = __expf(sc[0][r] - nm), p1 = __expf(sc[1][r] - nm);
            const float p2 = __expf(sc[2][r] - nm), p3 = __expf(sc[3][r] - nm);
            float ss = p0 + p1 + p2 + p3;
            #pragma unroll
            for (int d = 1; d < 16; d <<= 1) ss += __shfl_xor(ss, d, 64);
            lrun[r] = lrun[r] * esc + ss;
            #pragma unroll
            for (int n = 0; n < 4; ++n) oacc[n][r] *= esc;
            const int q = g * 4 + r;
            char* prow = PsW + q * 128;
            *(__bf16*)(prow + ((0 * 32 + ln * 2) ^ ((q & 7) << 4))) = (__bf16)p0;
            *(__bf16*)(prow + ((1 * 32 + ln * 2) ^ ((q & 7) << 4))) = (__bf16)p1;
            *(__bf16*)(prow + ((2 * 32 + ln * 2) ^ ((q & 7) << 4))) = (__bf16)p2;
            *(__bf16*)(prow + ((3 * 32 + ln * 2) ^ ((q & 7) << 4))) = (__bf16)p3;
        }

        // PV: O[q][d] += P[q][key] * V[key][d]   (B-frags from V^T rows = d)
        #pragma unroll
        for (int ks = 0; ks < 2; ++ks) {
            const bf16x8 pa = *reinterpret_cast<const bf16x8*>(
                PsW + ln * 128 + sw128(ln, ks * 64 + (g << 4)));
            #pragma unroll
            for (int n = 0; n < 4; ++n) {
                const int dr = n * 16 + ln;
                const bf16x8 vb_ = *reinterpret_cast<const bf16x8*>(
                    Vs + dr * 128 + sw128(dr, ks * 64 + (g << 4)));
                oacc[n] = __builtin_amdgcn_mfma_f32_16x16x32_bf16(pa, vb_, oacc[n], 0, 0, 0);
            }
        }
    }

    // epilogue: AO[b][s][h*64+d] (bf16)
    const int b = bh >> 4, h = bh & 15;
    #pragma unroll
    for (int r = 0; r < 4; ++r) {
        const int s = qt * 64 + w * 16 + g * 4 + r;
        const float inv = 1.0f / lrun[r];
        __bf16* orow = AO + ((size_t)(b * SEQ + s)) * DM + h * DKH;
        #pragma unroll
        for (int n = 0; n < 4; ++n)
            orow[n * 16 + ln] = (__bf16)(oacc[n][r] * inv);
    }
}

extern "C" void kernel_launch(void* const* d_in, const int* in_sizes, int n_in,
                              void* d_out, int out_size, void* d_ws, size_t ws_size,
                              hipStream_t stream)
{
    const float* q  = (const float*)d_in[0];
    const float* k  = (const float*)d_in[1];
    const float* v  = (const float*)d_in[2];
    const float* Wq = (const float*)d_in[3];
    const float* bq = (const float*)d_in[4];
    const float* Wk = (const float*)d_in[5];
    const float* bk = (const float*)d_in[6];
    const float* Wv = (const float*)d_in[7];
    const float* bv = (const float*)d_in[8];
    const float* Wo = (const float*)d_in[9];
    const float* bo = (const float*)d_in[10];
    float* out = (float*)d_out;

    const size_t NQ = (size_t)NB * SEQ * DM;  // 8,388,608
    const size_t NW = (size_t)DM * DM;        // 1,048,576

    __bf16* qb  = (__bf16*)d_ws;
    __bf16* kb  = qb + NQ;
    __bf16* vb  = kb + NQ;
    __bf16* Wqb = vb + NQ;
    __bf16* Wkb = Wqb + NW;
    __bf16* Wvb = Wkb + NW;
    __bf16* Wob = Wvb + NW;
    __bf16* Qp  = Wob + NW;
    __bf16* Kp  = Qp + NQ;
    __bf16* Vp  = Kp + NQ;
    __bf16* VtG = qb;  // alias: qb dead after Q-projection
    __bf16* AO  = kb;  // alias: kb dead after K-projection

    cvt_qkv<<<dim3(4096, 3), 256, 0, stream>>>(q, k, v, qb, kb, vb);
    cvt_w<<<dim3(512, 4), 256, 0, stream>>>(Wq, Wk, Wv, Wo, Wqb, Wkb, Wvb, Wob);

    dim3 gg(64, 8);
    gemm_bf16<0><<<gg, 256, 0, stream>>>(qb, Wqb, bq, 0.125f, Qp);
    gemm_bf16<0><<<gg, 256, 0, stream>>>(kb, Wkb, bk, 1.0f, Kp);
    gemm_bf16<0><<<gg, 256, 0, stream>>>(vb, Wvb, bv, 1.0f, Vp);
    transpose_v<<<dim3(32, 64), 256, 0, stream>>>(Vp, VtG);
    attn_mfma<<<dim3(32, 64), 256, 0, stream>>>(Qp, Kp, VtG, AO);
    gemm_bf16<1><<<gg, 256, 0, stream>>>(AO, Wob, bo, 1.0f, out);
}

// Round 3
// 395.862 us; speedup vs baseline: 5.0978x; 1.1978x over previous
//
#include <hip/hip_runtime.h>
#include <hip/hip_bf16.h>
#include <math.h>

// MHA forward, round 3: swapped-QK softmax + defer-max + exp2 + pipelined
// staging; GEMM upgraded to m97 structure (BK=64).
// B=4, S=2048, D=1024, H=16, dk=64.

#define SEQ 2048
#define NH 16
#define DKH 64
#define DM 1024
#define NB 4

// 0.125 * log2(e): fold scale AND exp->exp2 conversion into Wq/bq.
#define QSCALE 0.18033688011112042f

typedef float f32x4 __attribute__((ext_vector_type(4)));
typedef __bf16 bf16x8 __attribute__((ext_vector_type(8)));
typedef __bf16 bf16x2 __attribute__((ext_vector_type(2)));

#define GLOAD16(g, l)                                                          \
    __builtin_amdgcn_global_load_lds(                                          \
        (const __attribute__((address_space(1))) void*)(g),                    \
        (__attribute__((address_space(3))) void*)(l), 16, 0, 0)

__device__ __forceinline__ float fast_exp2(float x) {
    float r;
    asm("v_exp_f32 %0, %1" : "=v"(r) : "v"(x));
    return r;
}

// ===== fp32 -> bf16 conversion =====
__global__ __launch_bounds__(256) void cvt_qkv(
    const float* __restrict__ q, const float* __restrict__ k, const float* __restrict__ v,
    __bf16* __restrict__ qb, __bf16* __restrict__ kb, __bf16* __restrict__ vb)
{
    const float* src = blockIdx.y == 0 ? q : (blockIdx.y == 1 ? k : v);
    __bf16* dst      = blockIdx.y == 0 ? qb : (blockIdx.y == 1 ? kb : vb);
    const size_t i = ((size_t)blockIdx.x * 256 + threadIdx.x) * 8;
    const float4 a = *reinterpret_cast<const float4*>(src + i);
    const float4 b = *reinterpret_cast<const float4*>(src + i + 4);
    bf16x8 o;
    o[0] = (__bf16)a.x; o[1] = (__bf16)a.y; o[2] = (__bf16)a.z; o[3] = (__bf16)a.w;
    o[4] = (__bf16)b.x; o[5] = (__bf16)b.y; o[6] = (__bf16)b.z; o[7] = (__bf16)b.w;
    *reinterpret_cast<bf16x8*>(dst + i) = o;
}

__global__ __launch_bounds__(256) void cvt_w(
    const float* __restrict__ wq, const float* __restrict__ wk,
    const float* __restrict__ wv, const float* __restrict__ wo,
    __bf16* __restrict__ oq, __bf16* __restrict__ ok,
    __bf16* __restrict__ ov, __bf16* __restrict__ oo)
{
    const int y = blockIdx.y;
    const float* src = y == 0 ? wq : (y == 1 ? wk : (y == 2 ? wv : wo));
    __bf16* dst      = y == 0 ? oq : (y == 1 ? ok : (y == 2 ? ov : oo));
    const float scale = (y == 0) ? QSCALE : 1.0f;
    const size_t i = ((size_t)blockIdx.x * 256 + threadIdx.x) * 8;
    const float4 a = *reinterpret_cast<const float4*>(src + i);
    const float4 b = *reinterpret_cast<const float4*>(src + i + 4);
    bf16x8 o;
    o[0] = (__bf16)(a.x * scale); o[1] = (__bf16)(a.y * scale);
    o[2] = (__bf16)(a.z * scale); o[3] = (__bf16)(a.w * scale);
    o[4] = (__bf16)(b.x * scale); o[5] = (__bf16)(b.y * scale);
    o[6] = (__bf16)(b.z * scale); o[7] = (__bf16)(b.w * scale);
    *reinterpret_cast<bf16x8*>(dst + i) = o;
}

// ===== bf16 MFMA GEMM (m97 structure): C = A[M,K] @ W[N,K]^T + bias*bscale =====
// M=8192, N=K=1024. 128x128 tile, BK=64, 4 waves (2x2 of 64x64 quadrants).
// LAYOUT 0: bf16 head-split out[((b*16+h)*2048+s)*64+d]; LAYOUT 1: fp32 out[m*1024+n]
template <int LAYOUT>
__global__ __launch_bounds__(256) void gemm_bf16(
    const __bf16* __restrict__ A, const __bf16* __restrict__ W,
    const float* __restrict__ bias, float bscale, void* __restrict__ outv)
{
    __shared__ __align__(16) char As[16384];  // [128 rows][64 bf16], XOR-swizzled
    __shared__ __align__(16) char Bs[16384];
    const int t = threadIdx.x;
    const int w = t >> 6, lane = t & 63, g = lane >> 4, ln = lane & 15;
    const int bm = blockIdx.x, bn = blockIdx.y;
    const int wr = w >> 1, wc = w & 1;

    const int srow = t >> 3;                              // 0..31
    const int ssw  = ((t & 7) << 4) ^ ((srow & 7) << 4);  // pre-swizzled source col

    const char* Ag = (const char*)A + (size_t)(bm * 128 + srow) * 2048 + ssw;
    const char* Wg = (const char*)W + (size_t)(bn * 128 + srow) * 2048 + ssw;

    f32x4 acc[4][4];
    #pragma unroll
    for (int i = 0; i < 4; ++i)
        #pragma unroll
        for (int j = 0; j < 4; ++j)
            #pragma unroll
            for (int e = 0; e < 4; ++e) acc[i][j][e] = 0.0f;

    for (int kb = 0; kb < 16; ++kb) {
        __syncthreads();
        #pragma unroll
        for (int c = 0; c < 4; ++c) {
            GLOAD16(Ag + kb * 128 + (size_t)c * (32 * 2048), As + c * 4096 + t * 16);
            GLOAD16(Wg + kb * 128 + (size_t)c * (32 * 2048), Bs + c * 4096 + t * 16);
        }
        __syncthreads();
        #pragma unroll
        for (int ks = 0; ks < 2; ++ks) {
            bf16x8 a[4], b[4];
            #pragma unroll
            for (int mi = 0; mi < 4; ++mi) {
                const int row = wr * 64 + mi * 16 + ln;
                a[mi] = *reinterpret_cast<const bf16x8*>(
                    As + row * 128 + (((ks * 64) + (g << 4)) ^ ((row & 7) << 4)));
            }
            #pragma unroll
            for (int ni = 0; ni < 4; ++ni) {
                const int row = wc * 64 + ni * 16 + ln;
                b[ni] = *reinterpret_cast<const bf16x8*>(
                    Bs + row * 128 + (((ks * 64) + (g << 4)) ^ ((row & 7) << 4)));
            }
            #pragma unroll
            for (int mi = 0; mi < 4; ++mi)
                #pragma unroll
                for (int ni = 0; ni < 4; ++ni)
                    acc[mi][ni] = __builtin_amdgcn_mfma_f32_16x16x32_bf16(
                        a[mi], b[ni], acc[mi][ni], 0, 0, 0);
        }
    }

    const int gm0 = bm * 128 + wr * 64, gn0 = bn * 128 + wc * 64;
    #pragma unroll
    for (int mi = 0; mi < 4; ++mi)
        #pragma unroll
        for (int ni = 0; ni < 4; ++ni) {
            const int col = gn0 + ni * 16 + ln;
            const float bs = bias[col] * bscale;
            #pragma unroll
            for (int r = 0; r < 4; ++r) {
                const int row = gm0 + mi * 16 + g * 4 + r;
                const float val = acc[mi][ni][r] + bs;
                if (LAYOUT == 0) {
                    const int bb = row >> 11, s = row & 2047;
                    const int h = col >> 6, d = col & 63;
                    ((__bf16*)outv)[(((size_t)(bb * NH + h) * SEQ) + s) * DKH + d] = (__bf16)val;
                } else {
                    ((float*)outv)[(size_t)row * DM + col] = val;
                }
            }
        }
}

// ===== V transpose: Vp[bh][s][d] -> Vt[bh][d][s] (bf16) =====
__global__ __launch_bounds__(256) void transpose_v(
    const __bf16* __restrict__ Vp, __bf16* __restrict__ Vt)
{
    __shared__ __bf16 T[64][65];
    const int t = threadIdx.x, st = blockIdx.x, bh = blockIdx.y;
    const __bf16* src = Vp + ((size_t)bh * SEQ + st * 64) * DKH;
    #pragma unroll
    for (int r = 0; r < 2; ++r) {
        const int idx = r * 256 + t;
        const int s_l = idx >> 3, c8 = (idx & 7) << 3;
        const bf16x8 v8 = *reinterpret_cast<const bf16x8*>(src + s_l * DKH + c8);
        #pragma unroll
        for (int j = 0; j < 8; ++j) T[s_l][c8 + j] = v8[j];
    }
    __syncthreads();
    __bf16* dst = Vt + ((size_t)bh * DKH) * SEQ + st * 64;
    #pragma unroll
    for (int r = 0; r < 2; ++r) {
        const int idx = r * 256 + t;
        const int d = idx >> 3, s8 = (idx & 7) << 3;
        bf16x8 o;
        #pragma unroll
        for (int j = 0; j < 8; ++j) o[j] = T[s8 + j][d];
        *reinterpret_cast<bf16x8*>(dst + (size_t)d * SEQ + s8) = o;
    }
}

// ===== Flash attention, swapped-QK bf16 MFMA =====
// grid (32, 64), 256 thr = 4 waves; wave w owns q rows [w*16, w*16+16).
// Swapped QK^T: sc = mfma(K,Q) -> C[key][q], col=q=ln. Softmax state per q=ln.
// Double-buffered K/V staging, STAGE(next) before compute (T3-lite).
__global__ __launch_bounds__(256) void attn_mfma(
    const __bf16* __restrict__ Qp, const __bf16* __restrict__ Kp,
    const __bf16* __restrict__ Vt, __bf16* __restrict__ AO)
{
    __shared__ __align__(16) char Ks[16384];  // 2 x [64 key][64 dk] swizzled
    __shared__ __align__(16) char Vs[16384];  // 2 x [64 d][64 key] swizzled
    __shared__ __align__(16) char Ps[8192];   // 4 waves x [16 q][64 key] swizzled
    const int t = threadIdx.x;
    const int w = t >> 6, lane = t & 63, g = lane >> 4, ln = lane & 15;
    const int qt = blockIdx.x, bh = blockIdx.y;

    // Q fragments (B-operand): lane holds Q[q=ln][dk = ks*32 + g*8 ..+7]
    const __bf16* Qrow = Qp + ((size_t)bh * SEQ + qt * 64 + w * 16 + ln) * DKH;
    bf16x8 qf[2];
    qf[0] = *reinterpret_cast<const bf16x8*>(Qrow + g * 8);
    qf[1] = *reinterpret_cast<const bf16x8*>(Qrow + 32 + g * 8);

    // staging coords
    const int srow = t >> 3;                              // 0..31
    const int ssw  = ((t & 7) << 4) ^ ((srow & 7) << 4);
    const char* Kg = (const char*)Kp + ((size_t)bh * SEQ + srow) * 128 + ssw;
    const char* Vg = (const char*)Vt + ((size_t)bh * DKH + srow) * 4096 + ssw;

#define STAGE(buf, kt) do {                                                    \
        GLOAD16(Kg + (size_t)(kt) * 8192,          Ks + (buf) * 8192 + t * 16);\
        GLOAD16(Kg + (size_t)(kt) * 8192 + 4096,   Ks + (buf) * 8192 + 4096 + t * 16);\
        GLOAD16(Vg + (size_t)(kt) * 128,           Vs + (buf) * 8192 + t * 16);\
        GLOAD16(Vg + (size_t)(kt) * 128 + 32 * 4096, Vs + (buf) * 8192 + 4096 + t * 16);\
    } while (0)

    f32x4 oacc[4];
    float m = -INFINITY, l = 0.0f;
    #pragma unroll
    for (int n = 0; n < 4; ++n)
        #pragma unroll
        for (int e = 0; e < 4; ++e) oacc[n][e] = 0.0f;

    char* PsW = Ps + w * 2048;
    const int swm = (ln & 7) << 4;

    STAGE(0, 0);
    __syncthreads();

    int cur = 0;
    for (int kt = 0; kt < 32; ++kt) {
        if (kt + 1 < 32) STAGE(cur ^ 1, kt + 1);  // loads fly during compute

        const char* KsC = Ks + cur * 8192;
        const char* VsC = Vs + cur * 8192;

        // QK^T swapped: sc[f] = S^T tile, lane holds S[key=f*16+g*4+r][q=ln]
        f32x4 sc[4];
        #pragma unroll
        for (int f = 0; f < 4; ++f)
            #pragma unroll
            for (int e = 0; e < 4; ++e) sc[f][e] = 0.0f;
        #pragma unroll
        for (int ks = 0; ks < 2; ++ks)
            #pragma unroll
            for (int f = 0; f < 4; ++f) {
                const int kr = f * 16 + ln;
                const bf16x8 kf = *reinterpret_cast<const bf16x8*>(
                    KsC + kr * 128 + (((ks * 64) + (g << 4)) ^ ((kr & 7) << 4)));
                sc[f] = __builtin_amdgcn_mfma_f32_16x16x32_bf16(kf, qf[ks], sc[f], 0, 0, 0);
            }

        // prefetch V fragments (independent of softmax)
        bf16x8 vreg[2][4];
        #pragma unroll
        for (int ks = 0; ks < 2; ++ks)
            #pragma unroll
            for (int n = 0; n < 4; ++n) {
                const int dr = n * 16 + ln;
                vreg[ks][n] = *reinterpret_cast<const bf16x8*>(
                    VsC + dr * 128 + (((ks * 64) + (g << 4)) ^ ((dr & 7) << 4)));
            }

        // softmax (log2 domain), state owned by q=ln
        float t0 = fmaxf(fmaxf(sc[0][0], sc[0][1]), fmaxf(sc[0][2], sc[0][3]));
        float t1 = fmaxf(fmaxf(sc[1][0], sc[1][1]), fmaxf(sc[1][2], sc[1][3]));
        float t2 = fmaxf(fmaxf(sc[2][0], sc[2][1]), fmaxf(sc[2][2], sc[2][3]));
        float t3 = fmaxf(fmaxf(sc[3][0], sc[3][1]), fmaxf(sc[3][2], sc[3][3]));
        float tmax = fmaxf(fmaxf(t0, t1), fmaxf(t2, t3));
        tmax = fmaxf(tmax, __shfl_xor(tmax, 16, 64));
        tmax = fmaxf(tmax, __shfl_xor(tmax, 32, 64));

        if (__any(tmax > m + 11.0f)) {  // defer-max: rescale rarely
            const float mn = fmaxf(m, tmax);
            const float es = fast_exp2(m - mn);  // first tile: exp2(-inf)=0
            m = mn;
            l *= es;
            #pragma unroll
            for (int r = 0; r < 4; ++r) {
                const float er = __shfl(es, (lane & 48) + (g << 2) + r, 64);
                #pragma unroll
                for (int n = 0; n < 4; ++n) oacc[n][r] *= er;
            }
        }

        float p[4][4];
        float ss = 0.0f;
        #pragma unroll
        for (int f = 0; f < 4; ++f)
            #pragma unroll
            for (int r = 0; r < 4; ++r) {
                p[f][r] = fast_exp2(sc[f][r] - m);
                ss += p[f][r];
            }
        ss += __shfl_xor(ss, 16, 64);
        ss += __shfl_xor(ss, 32, 64);
        l += ss;

        // P -> LDS [q=ln][key], packed bf16x2, XOR-swizzled
        char* prow = PsW + ln * 128;
        #pragma unroll
        for (int f = 0; f < 4; ++f) {
            bf16x2 lo, hi;
            lo[0] = (__bf16)p[f][0]; lo[1] = (__bf16)p[f][1];
            hi[0] = (__bf16)p[f][2]; hi[1] = (__bf16)p[f][3];
            const int bc = f * 32 + (g << 3);
            *reinterpret_cast<bf16x2*>(prow + ((bc) ^ swm)) = lo;
            *reinterpret_cast<bf16x2*>(prow + ((bc + 4) ^ swm)) = hi;
        }

        // PV: O[q][d] += P[q][key] * V[key][d]
        #pragma unroll
        for (int ks = 0; ks < 2; ++ks) {
            const bf16x8 pa = *reinterpret_cast<const bf16x8*>(
                PsW + ln * 128 + (((ks * 64) + (g << 4)) ^ swm));
            #pragma unroll
            for (int n = 0; n < 4; ++n)
                oacc[n] = __builtin_amdgcn_mfma_f32_16x16x32_bf16(
                    pa, vreg[ks][n], oacc[n], 0, 0, 0);
        }

        __syncthreads();  // drains vmcnt (next buffer staged) + lgkm; gates overwrite
        cur ^= 1;
    }

    // epilogue: AO[b][s][h*64+d]; l/m live in lanes by q=ln -> shfl to rows
    const int b = bh >> 4, h = bh & 15;
    #pragma unroll
    for (int r = 0; r < 4; ++r) {
        const float lq = __shfl(l, (lane & 48) + (g << 2) + r, 64);
        const float inv = 1.0f / lq;
        const int s = qt * 64 + w * 16 + g * 4 + r;
        __bf16* orow = AO + ((size_t)(b * SEQ + s)) * DM + h * DKH;
        #pragma unroll
        for (int n = 0; n < 4; ++n)
            orow[n * 16 + ln] = (__bf16)(oacc[n][r] * inv);
    }
#undef STAGE
}

extern "C" void kernel_launch(void* const* d_in, const int* in_sizes, int n_in,
                              void* d_out, int out_size, void* d_ws, size_t ws_size,
                              hipStream_t stream)
{
    const float* q  = (const float*)d_in[0];
    const float* k  = (const float*)d_in[1];
    const float* v  = (const float*)d_in[2];
    const float* Wq = (const float*)d_in[3];
    const float* bq = (const float*)d_in[4];
    const float* Wk = (const float*)d_in[5];
    const float* bk = (const float*)d_in[6];
    const float* Wv = (const float*)d_in[7];
    const float* bv = (const float*)d_in[8];
    const float* Wo = (const float*)d_in[9];
    const float* bo = (const float*)d_in[10];
    float* out = (float*)d_out;

    const size_t NQ = (size_t)NB * SEQ * DM;  // 8,388,608
    const size_t NW = (size_t)DM * DM;        // 1,048,576

    __bf16* qb  = (__bf16*)d_ws;
    __bf16* kb  = qb + NQ;
    __bf16* vb  = kb + NQ;
    __bf16* Wqb = vb + NQ;
    __bf16* Wkb = Wqb + NW;
    __bf16* Wvb = Wkb + NW;
    __bf16* Wob = Wvb + NW;
    __bf16* Qp  = Wob + NW;
    __bf16* Kp  = Qp + NQ;
    __bf16* Vp  = Kp + NQ;
    __bf16* VtG = qb;  // alias: qb dead after Q-projection
    __bf16* AO  = kb;  // alias: kb dead after K-projection

    cvt_qkv<<<dim3(4096, 3), 256, 0, stream>>>(q, k, v, qb, kb, vb);
    cvt_w<<<dim3(512, 4), 256, 0, stream>>>(Wq, Wk, Wv, Wo, Wqb, Wkb, Wvb, Wob);

    dim3 gg(64, 8);
    gemm_bf16<0><<<gg, 256, 0, stream>>>(qb, Wqb, bq, QSCALE, Qp);
    gemm_bf16<0><<<gg, 256, 0, stream>>>(kb, Wkb, bk, 1.0f, Kp);
    gemm_bf16<0><<<gg, 256, 0, stream>>>(vb, Wvb, bv, 1.0f, Vp);
    transpose_v<<<dim3(32, 64), 256, 0, stream>>>(Vp, VtG);
    attn_mfma<<<dim3(32, 64), 256, 0, stream>>>(Qp, Kp, VtG, AO);
    gemm_bf16<1><<<gg, 256, 0, stream>>>(AO, Wob, bo, 1.0f, out);
}

// Round 4
// 384.952 us; speedup vs baseline: 5.2423x; 1.0283x over previous
//
#include <hip/hip_runtime.h>
#include <hip/hip_bf16.h>
#include <math.h>

// MHA forward, round 4: attn QBLK=128 (2 q-strips/wave), conflict-free P
// swizzle, fused QKV projection GEMM.
// B=4, S=2048, D=1024, H=16, dk=64.

#define SEQ 2048
#define NH 16
#define DKH 64
#define DM 1024
#define NB 4

// 0.125 * log2(e): fold scale AND exp->exp2 conversion into Wq/bq.
#define QSCALE 0.18033688011112042f

typedef float f32x4 __attribute__((ext_vector_type(4)));
typedef __bf16 bf16x8 __attribute__((ext_vector_type(8)));
typedef __bf16 bf16x4 __attribute__((ext_vector_type(4)));

#define GLOAD16(g, l)                                                          \
    __builtin_amdgcn_global_load_lds(                                          \
        (const __attribute__((address_space(1))) void*)(g),                    \
        (__attribute__((address_space(3))) void*)(l), 16, 0, 0)

__device__ __forceinline__ float fast_exp2(float x) {
    float r;
    asm("v_exp_f32 %0, %1" : "=v"(r) : "v"(x));
    return r;
}

// ===== fp32 -> bf16 conversion =====
__global__ __launch_bounds__(256) void cvt_qkv(
    const float* __restrict__ q, const float* __restrict__ k, const float* __restrict__ v,
    __bf16* __restrict__ qb, __bf16* __restrict__ kb, __bf16* __restrict__ vb)
{
    const float* src = blockIdx.y == 0 ? q : (blockIdx.y == 1 ? k : v);
    __bf16* dst      = blockIdx.y == 0 ? qb : (blockIdx.y == 1 ? kb : vb);
    const size_t i = ((size_t)blockIdx.x * 256 + threadIdx.x) * 8;
    const float4 a = *reinterpret_cast<const float4*>(src + i);
    const float4 b = *reinterpret_cast<const float4*>(src + i + 4);
    bf16x8 o;
    o[0] = (__bf16)a.x; o[1] = (__bf16)a.y; o[2] = (__bf16)a.z; o[3] = (__bf16)a.w;
    o[4] = (__bf16)b.x; o[5] = (__bf16)b.y; o[6] = (__bf16)b.z; o[7] = (__bf16)b.w;
    *reinterpret_cast<bf16x8*>(dst + i) = o;
}

__global__ __launch_bounds__(256) void cvt_w(
    const float* __restrict__ wq, const float* __restrict__ wk,
    const float* __restrict__ wv, const float* __restrict__ wo,
    __bf16* __restrict__ oq, __bf16* __restrict__ ok,
    __bf16* __restrict__ ov, __bf16* __restrict__ oo)
{
    const int y = blockIdx.y;
    const float* src = y == 0 ? wq : (y == 1 ? wk : (y == 2 ? wv : wo));
    __bf16* dst      = y == 0 ? oq : (y == 1 ? ok : (y == 2 ? ov : oo));
    const float scale = (y == 0) ? QSCALE : 1.0f;
    const size_t i = ((size_t)blockIdx.x * 256 + threadIdx.x) * 8;
    const float4 a = *reinterpret_cast<const float4*>(src + i);
    const float4 b = *reinterpret_cast<const float4*>(src + i + 4);
    bf16x8 o;
    o[0] = (__bf16)(a.x * scale); o[1] = (__bf16)(a.y * scale);
    o[2] = (__bf16)(a.z * scale); o[3] = (__bf16)(a.w * scale);
    o[4] = (__bf16)(b.x * scale); o[5] = (__bf16)(b.y * scale);
    o[6] = (__bf16)(b.z * scale); o[7] = (__bf16)(b.w * scale);
    *reinterpret_cast<bf16x8*>(dst + i) = o;
}

// ===== shared GEMM body: C = A[M,K] @ W[N,K]^T + bias*bscale =====
// 128x128 tile, BK=64, 4 waves (2x2 of 64x64 quadrants). M=8192, N=K=1024.
// LAYOUT 0: bf16 head-split out; LAYOUT 1: fp32 row-major out.
template <int LAYOUT>
__device__ __forceinline__ void gemm_body(
    const __bf16* __restrict__ A, const __bf16* __restrict__ W,
    const float* __restrict__ bias, float bscale, void* __restrict__ outv,
    char* As, char* Bs)
{
    const int t = threadIdx.x;
    const int w = t >> 6, lane = t & 63, g = lane >> 4, ln = lane & 15;
    const int bm = blockIdx.x, bn = blockIdx.y;
    const int wr = w >> 1, wc = w & 1;

    const int srow = t >> 3;                              // 0..31
    const int ssw  = ((t & 7) << 4) ^ ((srow & 7) << 4);  // pre-swizzled source col

    const char* Ag = (const char*)A + (size_t)(bm * 128 + srow) * 2048 + ssw;
    const char* Wg = (const char*)W + (size_t)(bn * 128 + srow) * 2048 + ssw;

    f32x4 acc[4][4];
    #pragma unroll
    for (int i = 0; i < 4; ++i)
        #pragma unroll
        for (int j = 0; j < 4; ++j)
            #pragma unroll
            for (int e = 0; e < 4; ++e) acc[i][j][e] = 0.0f;

    for (int kb = 0; kb < 16; ++kb) {
        __syncthreads();
        #pragma unroll
        for (int c = 0; c < 4; ++c) {
            GLOAD16(Ag + kb * 128 + (size_t)c * (32 * 2048), As + c * 4096 + t * 16);
            GLOAD16(Wg + kb * 128 + (size_t)c * (32 * 2048), Bs + c * 4096 + t * 16);
        }
        __syncthreads();
        #pragma unroll
        for (int ks = 0; ks < 2; ++ks) {
            bf16x8 a[4], b[4];
            #pragma unroll
            for (int mi = 0; mi < 4; ++mi) {
                const int row = wr * 64 + mi * 16 + ln;
                a[mi] = *reinterpret_cast<const bf16x8*>(
                    As + row * 128 + (((ks * 64) + (g << 4)) ^ ((row & 7) << 4)));
            }
            #pragma unroll
            for (int ni = 0; ni < 4; ++ni) {
                const int row = wc * 64 + ni * 16 + ln;
                b[ni] = *reinterpret_cast<const bf16x8*>(
                    Bs + row * 128 + (((ks * 64) + (g << 4)) ^ ((row & 7) << 4)));
            }
            #pragma unroll
            for (int mi = 0; mi < 4; ++mi)
                #pragma unroll
                for (int ni = 0; ni < 4; ++ni)
                    acc[mi][ni] = __builtin_amdgcn_mfma_f32_16x16x32_bf16(
                        a[mi], b[ni], acc[mi][ni], 0, 0, 0);
        }
    }

    const int gm0 = bm * 128 + wr * 64, gn0 = bn * 128 + wc * 64;
    #pragma unroll
    for (int mi = 0; mi < 4; ++mi)
        #pragma unroll
        for (int ni = 0; ni < 4; ++ni) {
            const int col = gn0 + ni * 16 + ln;
            const float bs = bias[col] * bscale;
            #pragma unroll
            for (int r = 0; r < 4; ++r) {
                const int row = gm0 + mi * 16 + g * 4 + r;
                const float val = acc[mi][ni][r] + bs;
                if (LAYOUT == 0) {
                    const int bb = row >> 11, s = row & 2047;
                    const int h = col >> 6, d = col & 63;
                    ((__bf16*)outv)[(((size_t)(bb * NH + h) * SEQ) + s) * DKH + d] = (__bf16)val;
                } else {
                    ((float*)outv)[(size_t)row * DM + col] = val;
                }
            }
        }
}

// Fused QKV projections: blockIdx.z selects which of the three GEMMs.
__global__ __launch_bounds__(256) void gemm_qkv(
    const __bf16* __restrict__ qb, const __bf16* __restrict__ kb, const __bf16* __restrict__ vb,
    const __bf16* __restrict__ Wqb, const __bf16* __restrict__ Wkb, const __bf16* __restrict__ Wvb,
    const float* __restrict__ bq, const float* __restrict__ bk, const float* __restrict__ bv,
    __bf16* __restrict__ Qp, __bf16* __restrict__ Kp, __bf16* __restrict__ Vp)
{
    __shared__ __align__(16) char As[16384];
    __shared__ __align__(16) char Bs[16384];
    const int z = blockIdx.z;
    const __bf16* A = z == 0 ? qb : (z == 1 ? kb : vb);
    const __bf16* W = z == 0 ? Wqb : (z == 1 ? Wkb : Wvb);
    const float* bias = z == 0 ? bq : (z == 1 ? bk : bv);
    __bf16* out = z == 0 ? Qp : (z == 1 ? Kp : Vp);
    const float bscale = z == 0 ? QSCALE : 1.0f;
    gemm_body<0>(A, W, bias, bscale, out, As, Bs);
}

__global__ __launch_bounds__(256) void gemm_out(
    const __bf16* __restrict__ A, const __bf16* __restrict__ W,
    const float* __restrict__ bias, float* __restrict__ out)
{
    __shared__ __align__(16) char As[16384];
    __shared__ __align__(16) char Bs[16384];
    gemm_body<1>(A, W, bias, 1.0f, out, As, Bs);
}

// ===== V transpose: Vp[bh][s][d] -> Vt[bh][d][s] (bf16) =====
__global__ __launch_bounds__(256) void transpose_v(
    const __bf16* __restrict__ Vp, __bf16* __restrict__ Vt)
{
    __shared__ __bf16 T[64][65];
    const int t = threadIdx.x, st = blockIdx.x, bh = blockIdx.y;
    const __bf16* src = Vp + ((size_t)bh * SEQ + st * 64) * DKH;
    #pragma unroll
    for (int r = 0; r < 2; ++r) {
        const int idx = r * 256 + t;
        const int s_l = idx >> 3, c8 = (idx & 7) << 3;
        const bf16x8 v8 = *reinterpret_cast<const bf16x8*>(src + s_l * DKH + c8);
        #pragma unroll
        for (int j = 0; j < 8; ++j) T[s_l][c8 + j] = v8[j];
    }
    __syncthreads();
    __bf16* dst = Vt + ((size_t)bh * DKH) * SEQ + st * 64;
    #pragma unroll
    for (int r = 0; r < 2; ++r) {
        const int idx = r * 256 + t;
        const int d = idx >> 3, s8 = (idx & 7) << 3;
        bf16x8 o;
        #pragma unroll
        for (int j = 0; j < 8; ++j) o[j] = T[s8 + j][d];
        *reinterpret_cast<bf16x8*>(dst + (size_t)d * SEQ + s8) = o;
    }
}

// ===== Flash attention, swapped-QK bf16 MFMA, QBLK=128 =====
// grid (16, 64), 256 thr = 4 waves. Wave w owns q-strips {qt*128 + st*64 +
// w*16 .. +16} for st=0,1. Swapped QK^T: sc = mfma(K,Q) -> C[key][q], col=q=ln.
__global__ __launch_bounds__(256) void attn_mfma(
    const __bf16* __restrict__ Qp, const __bf16* __restrict__ Kp,
    const __bf16* __restrict__ Vt, __bf16* __restrict__ AO)
{
    __shared__ __align__(16) char Ks[16384];  // 2 x [64 key][64 dk] swizzled
    __shared__ __align__(16) char Vs[16384];  // 2 x [64 d][64 key] swizzled
    __shared__ __align__(16) char Ps[16384];  // 4 waves x 2 strips x [16 q][64 key]
    const int t = threadIdx.x;
    const int w = t >> 6, lane = t & 63, g = lane >> 4, ln = lane & 15;
    const int qt = blockIdx.x, bh = blockIdx.y;

    // Q fragments (B-operand): lane holds Q[q=ln][dk = ks*32 + g*8 ..+7]
    bf16x8 qf[2][2];
    #pragma unroll
    for (int st = 0; st < 2; ++st) {
        const __bf16* Qrow =
            Qp + ((size_t)bh * SEQ + qt * 128 + st * 64 + w * 16 + ln) * DKH;
        qf[st][0] = *reinterpret_cast<const bf16x8*>(Qrow + g * 8);
        qf[st][1] = *reinterpret_cast<const bf16x8*>(Qrow + 32 + g * 8);
    }

    // staging coords
    const int srow = t >> 3;                              // 0..31
    const int ssw  = ((t & 7) << 4) ^ ((srow & 7) << 4);
    const char* Kg = (const char*)Kp + ((size_t)bh * SEQ + srow) * 128 + ssw;
    const char* Vg = (const char*)Vt + ((size_t)bh * DKH + srow) * 4096 + ssw;

#define STAGE(buf, kt) do {                                                    \
        GLOAD16(Kg + (size_t)(kt) * 8192,          Ks + (buf) * 8192 + t * 16);\
        GLOAD16(Kg + (size_t)(kt) * 8192 + 4096,   Ks + (buf) * 8192 + 4096 + t * 16);\
        GLOAD16(Vg + (size_t)(kt) * 128,           Vs + (buf) * 8192 + t * 16);\
        GLOAD16(Vg + (size_t)(kt) * 128 + 32 * 4096, Vs + (buf) * 8192 + 4096 + t * 16);\
    } while (0)

    f32x4 oacc[2][4];
    float m[2] = {-INFINITY, -INFINITY}, l[2] = {0.0f, 0.0f};
    #pragma unroll
    for (int st = 0; st < 2; ++st)
        #pragma unroll
        for (int n = 0; n < 4; ++n)
            #pragma unroll
            for (int e = 0; e < 4; ++e) oacc[st][n][e] = 0.0f;

    char* PsW = Ps + w * 4096;          // 2 strips x 2KB
    const int swp = (ln & 3) << 5;      // P swizzle (conflict-free both sides)

    STAGE(0, 0);
    __syncthreads();

    int cur = 0;
    for (int kt = 0; kt < 32; ++kt) {
        if (kt + 1 < 32) STAGE(cur ^ 1, kt + 1);  // loads fly during compute

        const char* KsC = Ks + cur * 8192;
        const char* VsC = Vs + cur * 8192;

        // K fragments (shared by both strips)
        bf16x8 kf[2][4];
        #pragma unroll
        for (int ks = 0; ks < 2; ++ks)
            #pragma unroll
            for (int f = 0; f < 4; ++f) {
                const int kr = f * 16 + ln;
                kf[ks][f] = *reinterpret_cast<const bf16x8*>(
                    KsC + kr * 128 + (((ks * 64) + (g << 4)) ^ ((kr & 7) << 4)));
            }

        // QK^T swapped, both strips: lane holds S[key=f*16+g*4+r][q=ln]
        f32x4 sc[2][4];
        #pragma unroll
        for (int st = 0; st < 2; ++st)
            #pragma unroll
            for (int f = 0; f < 4; ++f)
                #pragma unroll
                for (int e = 0; e < 4; ++e) sc[st][f][e] = 0.0f;
        #pragma unroll
        for (int ks = 0; ks < 2; ++ks)
            #pragma unroll
            for (int st = 0; st < 2; ++st)
                #pragma unroll
                for (int f = 0; f < 4; ++f)
                    sc[st][f] = __builtin_amdgcn_mfma_f32_16x16x32_bf16(
                        kf[ks][f], qf[st][ks], sc[st][f], 0, 0, 0);

        // V fragments (shared by both strips)
        bf16x8 vreg[2][4];
        #pragma unroll
        for (int ks = 0; ks < 2; ++ks)
            #pragma unroll
            for (int n = 0; n < 4; ++n) {
                const int dr = n * 16 + ln;
                vreg[ks][n] = *reinterpret_cast<const bf16x8*>(
                    VsC + dr * 128 + (((ks * 64) + (g << 4)) ^ ((dr & 7) << 4)));
            }

        // softmax + P store per strip (VALU overlaps MFMA tail / P lgkm waits)
        #pragma unroll
        for (int st = 0; st < 2; ++st) {
            float t0 = fmaxf(fmaxf(sc[st][0][0], sc[st][0][1]), fmaxf(sc[st][0][2], sc[st][0][3]));
            float t1 = fmaxf(fmaxf(sc[st][1][0], sc[st][1][1]), fmaxf(sc[st][1][2], sc[st][1][3]));
            float t2 = fmaxf(fmaxf(sc[st][2][0], sc[st][2][1]), fmaxf(sc[st][2][2], sc[st][2][3]));
            float t3 = fmaxf(fmaxf(sc[st][3][0], sc[st][3][1]), fmaxf(sc[st][3][2], sc[st][3][3]));
            float tmax = fmaxf(fmaxf(t0, t1), fmaxf(t2, t3));
            tmax = fmaxf(tmax, __shfl_xor(tmax, 16, 64));
            tmax = fmaxf(tmax, __shfl_xor(tmax, 32, 64));

            if (__any(tmax > m[st] + 11.0f)) {  // defer-max: rescale rarely
                const float mn = fmaxf(m[st], tmax);
                const float es = fast_exp2(m[st] - mn);  // first tile: 0
                m[st] = mn;
                l[st] *= es;
                #pragma unroll
                for (int r = 0; r < 4; ++r) {
                    const float er = __shfl(es, (lane & 48) + (g << 2) + r, 64);
                    #pragma unroll
                    for (int n = 0; n < 4; ++n) oacc[st][n][r] *= er;
                }
            }

            float ss = 0.0f;
            char* prow = PsW + st * 2048 + ln * 128;
            #pragma unroll
            for (int f = 0; f < 4; ++f) {
                float p0 = fast_exp2(sc[st][f][0] - m[st]);
                float p1 = fast_exp2(sc[st][f][1] - m[st]);
                float p2 = fast_exp2(sc[st][f][2] - m[st]);
                float p3 = fast_exp2(sc[st][f][3] - m[st]);
                ss += (p0 + p1) + (p2 + p3);
                bf16x4 pk;
                pk[0] = (__bf16)p0; pk[1] = (__bf16)p1;
                pk[2] = (__bf16)p2; pk[3] = (__bf16)p3;
                *reinterpret_cast<bf16x4*>(prow + ((f * 32 + g * 8) ^ swp)) = pk;
            }
            ss += __shfl_xor(ss, 16, 64);
            ss += __shfl_xor(ss, 32, 64);
            l[st] += ss;
        }

        // PV both strips: O[q][d] += P[q][key] * V[key][d]
        #pragma unroll
        for (int st = 0; st < 2; ++st)
            #pragma unroll
            for (int ks = 0; ks < 2; ++ks) {
                const bf16x8 pa = *reinterpret_cast<const bf16x8*>(
                    PsW + st * 2048 + ln * 128 + (((ks * 64) + (g << 4)) ^ swp));
                #pragma unroll
                for (int n = 0; n < 4; ++n)
                    oacc[st][n] = __builtin_amdgcn_mfma_f32_16x16x32_bf16(
                        pa, vreg[ks][n], oacc[st][n], 0, 0, 0);
            }

        __syncthreads();  // next buffer staged + P consumed; gates overwrite
        cur ^= 1;
    }

    // epilogue: AO[b][s][h*64+d]; l lives by q=ln -> shfl to C rows
    const int b = bh >> 4, h = bh & 15;
    #pragma unroll
    for (int st = 0; st < 2; ++st)
        #pragma unroll
        for (int r = 0; r < 4; ++r) {
            const float lq = __shfl(l[st], (lane & 48) + (g << 2) + r, 64);
            const float inv = 1.0f / lq;
            const int s = qt * 128 + st * 64 + w * 16 + g * 4 + r;
            __bf16* orow = AO + ((size_t)(b * SEQ + s)) * DM + h * DKH;
            #pragma unroll
            for (int n = 0; n < 4; ++n)
                orow[n * 16 + ln] = (__bf16)(oacc[st][n][r] * inv);
        }
#undef STAGE
}

extern "C" void kernel_launch(void* const* d_in, const int* in_sizes, int n_in,
                              void* d_out, int out_size, void* d_ws, size_t ws_size,
                              hipStream_t stream)
{
    const float* q  = (const float*)d_in[0];
    const float* k  = (const float*)d_in[1];
    const float* v  = (const float*)d_in[2];
    const float* Wq = (const float*)d_in[3];
    const float* bq = (const float*)d_in[4];
    const float* Wk = (const float*)d_in[5];
    const float* bk = (const float*)d_in[6];
    const float* Wv = (const float*)d_in[7];
    const float* bv = (const float*)d_in[8];
    const float* Wo = (const float*)d_in[9];
    const float* bo = (const float*)d_in[10];
    float* out = (float*)d_out;

    const size_t NQ = (size_t)NB * SEQ * DM;  // 8,388,608
    const size_t NW = (size_t)DM * DM;        // 1,048,576

    __bf16* qb  = (__bf16*)d_ws;
    __bf16* kb  = qb + NQ;
    __bf16* vb  = kb + NQ;
    __bf16* Wqb = vb + NQ;
    __bf16* Wkb = Wqb + NW;
    __bf16* Wvb = Wkb + NW;
    __bf16* Wob = Wvb + NW;
    __bf16* Qp  = Wob + NW;
    __bf16* Kp  = Qp + NQ;
    __bf16* Vp  = Kp + NQ;
    __bf16* VtG = qb;  // alias: qb dead after Q-projection
    __bf16* AO  = kb;  // alias: kb dead after K-projection

    cvt_qkv<<<dim3(4096, 3), 256, 0, stream>>>(q, k, v, qb, kb, vb);
    cvt_w<<<dim3(512, 4), 256, 0, stream>>>(Wq, Wk, Wv, Wo, Wqb, Wkb, Wvb, Wob);

    gemm_qkv<<<dim3(64, 8, 3), 256, 0, stream>>>(qb, kb, vb, Wqb, Wkb, Wvb,
                                                 bq, bk, bv, Qp, Kp, Vp);
    transpose_v<<<dim3(32, 64), 256, 0, stream>>>(Vp, VtG);
    attn_mfma<<<dim3(16, 64), 256, 0, stream>>>(Qp, Kp, VtG, AO);
    gemm_out<<<dim3(64, 8), 256, 0, stream>>>(AO, Wob, bo, out);
}

// Round 5
// 376.503 us; speedup vs baseline: 5.3600x; 1.0224x over previous
//
#include <hip/hip_runtime.h>
#include <hip/hip_bf16.h>
#include <math.h>

// MHA forward, round 5: attn on 32x32 MFMA with in-register P (cvt_pk +
// permlane32_swap, no P-LDS); GEMMs double-buffered with early STAGE issue.
// B=4, S=2048, D=1024, H=16, dk=64.

#define SEQ 2048
#define NH 16
#define DKH 64
#define DM 1024
#define NB 4

// 0.125 * log2(e): fold scale AND exp->exp2 conversion into Wq/bq.
#define QSCALE 0.18033688011112042f

typedef float f32x4 __attribute__((ext_vector_type(4)));
typedef float f32x16 __attribute__((ext_vector_type(16)));
typedef __bf16 bf16x8 __attribute__((ext_vector_type(8)));
typedef unsigned int u32x4 __attribute__((ext_vector_type(4)));

#define GLOAD16(g, l)                                                          \
    __builtin_amdgcn_global_load_lds(                                          \
        (const __attribute__((address_space(1))) void*)(g),                    \
        (__attribute__((address_space(3))) void*)(l), 16, 0, 0)

__device__ __forceinline__ float fast_exp2(float x) {
    float r;
    asm("v_exp_f32 %0, %1" : "=v"(r) : "v"(x));
    return r;
}
__device__ __forceinline__ unsigned cvt_pk_bf16(float lo, float hi) {
    unsigned r;
    asm("v_cvt_pk_bf16_f32 %0, %1, %2" : "=v"(r) : "v"(lo), "v"(hi));
    return r;
}
// a' = {lo: a_lo, hi: b_lo}; b' = {lo: a_hi, hi: b_hi}
__device__ __forceinline__ void permlane32_swap(unsigned& a, unsigned& b) {
    asm("v_permlane32_swap_b32 %0, %1" : "+v"(a), "+v"(b));
}

// ===== fp32 -> bf16 conversion =====
__global__ __launch_bounds__(256) void cvt_qkv(
    const float* __restrict__ q, const float* __restrict__ k, const float* __restrict__ v,
    __bf16* __restrict__ qb, __bf16* __restrict__ kb, __bf16* __restrict__ vb)
{
    const float* src = blockIdx.y == 0 ? q : (blockIdx.y == 1 ? k : v);
    __bf16* dst      = blockIdx.y == 0 ? qb : (blockIdx.y == 1 ? kb : vb);
    const size_t i = ((size_t)blockIdx.x * 256 + threadIdx.x) * 8;
    const float4 a = *reinterpret_cast<const float4*>(src + i);
    const float4 b = *reinterpret_cast<const float4*>(src + i + 4);
    bf16x8 o;
    o[0] = (__bf16)a.x; o[1] = (__bf16)a.y; o[2] = (__bf16)a.z; o[3] = (__bf16)a.w;
    o[4] = (__bf16)b.x; o[5] = (__bf16)b.y; o[6] = (__bf16)b.z; o[7] = (__bf16)b.w;
    *reinterpret_cast<bf16x8*>(dst + i) = o;
}

__global__ __launch_bounds__(256) void cvt_w(
    const float* __restrict__ wq, const float* __restrict__ wk,
    const float* __restrict__ wv, const float* __restrict__ wo,
    __bf16* __restrict__ oq, __bf16* __restrict__ ok,
    __bf16* __restrict__ ov, __bf16* __restrict__ oo)
{
    const int y = blockIdx.y;
    const float* src = y == 0 ? wq : (y == 1 ? wk : (y == 2 ? wv : wo));
    __bf16* dst      = y == 0 ? oq : (y == 1 ? ok : (y == 2 ? ov : oo));
    const float scale = (y == 0) ? QSCALE : 1.0f;
    const size_t i = ((size_t)blockIdx.x * 256 + threadIdx.x) * 8;
    const float4 a = *reinterpret_cast<const float4*>(src + i);
    const float4 b = *reinterpret_cast<const float4*>(src + i + 4);
    bf16x8 o;
    o[0] = (__bf16)(a.x * scale); o[1] = (__bf16)(a.y * scale);
    o[2] = (__bf16)(a.z * scale); o[3] = (__bf16)(a.w * scale);
    o[4] = (__bf16)(b.x * scale); o[5] = (__bf16)(b.y * scale);
    o[6] = (__bf16)(b.z * scale); o[7] = (__bf16)(b.w * scale);
    *reinterpret_cast<bf16x8*>(dst + i) = o;
}

// ===== shared GEMM body: C = A[M,K] @ W[N,K]^T + bias*bscale =====
// 128x128 tile, BK=64, 4 waves. Double-buffered LDS; STAGE(next) issued
// before compute so the end-of-iter barrier drain is covered by compute.
template <int LAYOUT>
__device__ __forceinline__ void gemm_body(
    const __bf16* __restrict__ A, const __bf16* __restrict__ W,
    const float* __restrict__ bias, float bscale, void* __restrict__ outv,
    char* As, char* Bs)  // each 32768 B (2 buffers x 16384)
{
    const int t = threadIdx.x;
    const int w = t >> 6, lane = t & 63, g = lane >> 4, ln = lane & 15;
    const int bm = blockIdx.x, bn = blockIdx.y;
    const int wr = w >> 1, wc = w & 1;

    const int srow = t >> 3;                              // 0..31
    const int ssw  = ((t & 7) << 4) ^ ((srow & 7) << 4);  // pre-swizzled source col

    const char* Ag = (const char*)A + (size_t)(bm * 128 + srow) * 2048 + ssw;
    const char* Wg = (const char*)W + (size_t)(bn * 128 + srow) * 2048 + ssw;

#define GSTAGE(buf, kb) do {                                                   \
        _Pragma("unroll")                                                      \
        for (int c = 0; c < 4; ++c) {                                          \
            GLOAD16(Ag + (kb) * 128 + (size_t)c * (32 * 2048),                 \
                    As + (buf) * 16384 + c * 4096 + t * 16);                   \
            GLOAD16(Wg + (kb) * 128 + (size_t)c * (32 * 2048),                 \
                    Bs + (buf) * 16384 + c * 4096 + t * 16);                   \
        }                                                                      \
    } while (0)

    f32x4 acc[4][4];
    #pragma unroll
    for (int i = 0; i < 4; ++i)
        #pragma unroll
        for (int j = 0; j < 4; ++j)
            #pragma unroll
            for (int e = 0; e < 4; ++e) acc[i][j][e] = 0.0f;

    GSTAGE(0, 0);
    int cur = 0;
    for (int kb = 0; kb < 16; ++kb) {
        __syncthreads();                      // buffer[cur] loads complete
        if (kb + 1 < 16) GSTAGE(cur ^ 1, kb + 1);  // next-tile loads in flight

        const char* AsC = As + cur * 16384;
        const char* BsC = Bs + cur * 16384;
        #pragma unroll
        for (int ks = 0; ks < 2; ++ks) {
            bf16x8 a[4], b[4];
            #pragma unroll
            for (int mi = 0; mi < 4; ++mi) {
                const int row = wr * 64 + mi * 16 + ln;
                a[mi] = *reinterpret_cast<const bf16x8*>(
                    AsC + row * 128 + (((ks * 64) + (g << 4)) ^ ((row & 7) << 4)));
            }
            #pragma unroll
            for (int ni = 0; ni < 4; ++ni) {
                const int row = wc * 64 + ni * 16 + ln;
                b[ni] = *reinterpret_cast<const bf16x8*>(
                    BsC + row * 128 + (((ks * 64) + (g << 4)) ^ ((row & 7) << 4)));
            }
            __builtin_amdgcn_s_setprio(1);
            #pragma unroll
            for (int mi = 0; mi < 4; ++mi)
                #pragma unroll
                for (int ni = 0; ni < 4; ++ni)
                    acc[mi][ni] = __builtin_amdgcn_mfma_f32_16x16x32_bf16(
                        a[mi], b[ni], acc[mi][ni], 0, 0, 0);
            __builtin_amdgcn_s_setprio(0);
        }
        cur ^= 1;
    }
#undef GSTAGE

    const int gm0 = bm * 128 + wr * 64, gn0 = bn * 128 + wc * 64;
    #pragma unroll
    for (int mi = 0; mi < 4; ++mi)
        #pragma unroll
        for (int ni = 0; ni < 4; ++ni) {
            const int col = gn0 + ni * 16 + ln;
            const float bs = bias[col] * bscale;
            #pragma unroll
            for (int r = 0; r < 4; ++r) {
                const int row = gm0 + mi * 16 + g * 4 + r;
                const float val = acc[mi][ni][r] + bs;
                if (LAYOUT == 0) {
                    const int bb = row >> 11, s = row & 2047;
                    const int h = col >> 6, d = col & 63;
                    ((__bf16*)outv)[(((size_t)(bb * NH + h) * SEQ) + s) * DKH + d] = (__bf16)val;
                } else {
                    ((float*)outv)[(size_t)row * DM + col] = val;
                }
            }
        }
}

__global__ __launch_bounds__(256) void gemm_qkv(
    const __bf16* __restrict__ qb, const __bf16* __restrict__ kb, const __bf16* __restrict__ vb,
    const __bf16* __restrict__ Wqb, const __bf16* __restrict__ Wkb, const __bf16* __restrict__ Wvb,
    const float* __restrict__ bq, const float* __restrict__ bk, const float* __restrict__ bv,
    __bf16* __restrict__ Qp, __bf16* __restrict__ Kp, __bf16* __restrict__ Vp)
{
    __shared__ __align__(16) char As[32768];
    __shared__ __align__(16) char Bs[32768];
    const int z = blockIdx.z;
    const __bf16* A = z == 0 ? qb : (z == 1 ? kb : vb);
    const __bf16* W = z == 0 ? Wqb : (z == 1 ? Wkb : Wvb);
    const float* bias = z == 0 ? bq : (z == 1 ? bk : bv);
    __bf16* out = z == 0 ? Qp : (z == 1 ? Kp : Vp);
    const float bscale = z == 0 ? QSCALE : 1.0f;
    gemm_body<0>(A, W, bias, bscale, out, As, Bs);
}

__global__ __launch_bounds__(256) void gemm_out(
    const __bf16* __restrict__ A, const __bf16* __restrict__ W,
    const float* __restrict__ bias, float* __restrict__ out)
{
    __shared__ __align__(16) char As[32768];
    __shared__ __align__(16) char Bs[32768];
    gemm_body<1>(A, W, bias, 1.0f, out, As, Bs);
}

// ===== V transpose: Vp[bh][s][d] -> Vt[bh][d][s] (bf16) =====
__global__ __launch_bounds__(256) void transpose_v(
    const __bf16* __restrict__ Vp, __bf16* __restrict__ Vt)
{
    __shared__ __bf16 T[64][65];
    const int t = threadIdx.x, st = blockIdx.x, bh = blockIdx.y;
    const __bf16* src = Vp + ((size_t)bh * SEQ + st * 64) * DKH;
    #pragma unroll
    for (int r = 0; r < 2; ++r) {
        const int idx = r * 256 + t;
        const int s_l = idx >> 3, c8 = (idx & 7) << 3;
        const bf16x8 v8 = *reinterpret_cast<const bf16x8*>(src + s_l * DKH + c8);
        #pragma unroll
        for (int j = 0; j < 8; ++j) T[s_l][c8 + j] = v8[j];
    }
    __syncthreads();
    __bf16* dst = Vt + ((size_t)bh * DKH) * SEQ + st * 64;
    #pragma unroll
    for (int r = 0; r < 2; ++r) {
        const int idx = r * 256 + t;
        const int d = idx >> 3, s8 = (idx & 7) << 3;
        bf16x8 o;
        #pragma unroll
        for (int j = 0; j < 8; ++j) o[j] = T[s8 + j][d];
        *reinterpret_cast<bf16x8*>(dst + (size_t)d * SEQ + s8) = o;
    }
}

// ===== Flash attention, 32x32 MFMA, swapped QK, in-register P (T12) =====
// grid (16, 64), 256 thr = 4 waves; wave w owns q rows [qt*128+w*32, +32).
// sc = mfma(K,Q): C[key][q], col = q = lane&31 -> softmax is in-lane + one
// lane^32 exchange. P never touches LDS: cvt_pk + permlane32_swap builds the
// PV A-fragments in registers.
__global__ __launch_bounds__(256) void attn_mfma(
    const __bf16* __restrict__ Qp, const __bf16* __restrict__ Kp,
    const __bf16* __restrict__ Vt, __bf16* __restrict__ AO)
{
    __shared__ __align__(16) char Ks[16384];  // 2 x [64 key][64 dk] swizzled
    __shared__ __align__(16) char Vs[16384];  // 2 x [64 d][64 key] swizzled
    const int t = threadIdx.x;
    const int w = t >> 6, lane = t & 63, q5 = lane & 31, h = lane >> 5;
    const int qt = blockIdx.x, bh = blockIdx.y;

    // Q frags (B-operand): lane holds Q[q=q5][dk = ksc*16 + h*8 + e]
    const __bf16* Qrow = Qp + ((size_t)bh * SEQ + qt * 128 + w * 32 + q5) * DKH;
    bf16x8 qf[4];
    #pragma unroll
    for (int ksc = 0; ksc < 4; ++ksc)
        qf[ksc] = *reinterpret_cast<const bf16x8*>(Qrow + ksc * 16 + h * 8);

    // staging coords (same as round 4)
    const int srow = t >> 3;                              // 0..31
    const int ssw  = ((t & 7) << 4) ^ ((srow & 7) << 4);
    const char* Kg = (const char*)Kp + ((size_t)bh * SEQ + srow) * 128 + ssw;
    const char* Vg = (const char*)Vt + ((size_t)bh * DKH + srow) * 4096 + ssw;

#define STAGE(buf, kt) do {                                                    \
        GLOAD16(Kg + (size_t)(kt) * 8192,            Ks + (buf) * 8192 + t * 16);\
        GLOAD16(Kg + (size_t)(kt) * 8192 + 4096,     Ks + (buf) * 8192 + 4096 + t * 16);\
        GLOAD16(Vg + (size_t)(kt) * 128,             Vs + (buf) * 8192 + t * 16);\
        GLOAD16(Vg + (size_t)(kt) * 128 + 32 * 4096, Vs + (buf) * 8192 + 4096 + t * 16);\
    } while (0)

    f32x16 oacc[2];
    float m = -INFINITY, lsum = 0.0f;
    #pragma unroll
    for (int jb = 0; jb < 2; ++jb)
        #pragma unroll
        for (int e = 0; e < 16; ++e) oacc[jb][e] = 0.0f;

    STAGE(0, 0);
    __syncthreads();

    int cur = 0;
    for (int kt = 0; kt < 32; ++kt) {
        if (kt + 1 < 32) STAGE(cur ^ 1, kt + 1);  // loads fly during compute

        const char* KsC = Ks + cur * 8192;
        const char* VsC = Vs + cur * 8192;

        // QK^T swapped: sc0/sc1 = S^T for keys [0,32)/[32,64).
        // lane holds S[key = kb*32 + (r&3)+8*(r>>2)+4*h][q = q5]
        f32x16 sc0, sc1;
        #pragma unroll
        for (int e = 0; e < 16; ++e) { sc0[e] = 0.0f; sc1[e] = 0.0f; }
        const int ksw = (q5 & 7) << 4;
        __builtin_amdgcn_s_setprio(1);
        #pragma unroll
        for (int ksc = 0; ksc < 4; ++ksc) {
            const bf16x8 kf0 = *reinterpret_cast<const bf16x8*>(
                KsC + q5 * 128 + ((ksc * 32 + h * 16) ^ ksw));
            const bf16x8 kf1 = *reinterpret_cast<const bf16x8*>(
                KsC + (32 + q5) * 128 + ((ksc * 32 + h * 16) ^ ksw));
            sc0 = __builtin_amdgcn_mfma_f32_32x32x16_bf16(kf0, qf[ksc], sc0, 0, 0, 0);
            sc1 = __builtin_amdgcn_mfma_f32_32x32x16_bf16(kf1, qf[ksc], sc1, 0, 0, 0);
        }
        __builtin_amdgcn_s_setprio(0);

        // softmax (log2 domain), state owned by q=q5 (same in both halves)
        float tmax = fmaxf(sc0[0], sc1[0]);
        #pragma unroll
        for (int e = 1; e < 16; ++e) tmax = fmaxf(tmax, fmaxf(sc0[e], sc1[e]));
        tmax = fmaxf(tmax, __shfl_xor(tmax, 32, 64));

        if (__any(tmax > m + 11.0f)) {  // defer-max: rescale rarely
            const float mn = fmaxf(m, tmax);
            const float es = fast_exp2(m - mn);  // first tile: exp2(-inf)=0
            m = mn;
            lsum *= es;
            #pragma unroll
            for (int r = 0; r < 16; ++r) {
                const float er = __shfl(es, (r & 3) + 8 * (r >> 2) + 4 * h, 64);
                oacc[0][r] *= er;
                oacc[1][r] *= er;
            }
        }

        float p0[16], p1[16];
        float ss = 0.0f;
        #pragma unroll
        for (int e = 0; e < 16; ++e) {
            p0[e] = fast_exp2(sc0[e] - m);
            p1[e] = fast_exp2(sc1[e] - m);
            ss += p0[e] + p1[e];
        }
        ss += __shfl_xor(ss, 32, 64);
        lsum += ss;

        // T12: build PV A-frags in registers. For kbp (16-key chunk):
        //   word(j)   = cvtpk(p[base+2j], p[base+2j+1])      (target lo half)
        //   word(j)+4 = cvtpk(p[base+2j+4], p[base+2j+5])    (target hi half)
        //   permlane32_swap(a,b) -> a = frag word j, b = frag word j+2
        bf16x8 pa[4];
        #pragma unroll
        for (int kbp = 0; kbp < 4; ++kbp) {
            const float* ps = (kbp >> 1) ? p1 : p0;
            const int base = 8 * (kbp & 1);
            unsigned a0 = cvt_pk_bf16(ps[base + 0], ps[base + 1]);
            unsigned b0 = cvt_pk_bf16(ps[base + 4], ps[base + 5]);
            unsigned a1 = cvt_pk_bf16(ps[base + 2], ps[base + 3]);
            unsigned b1 = cvt_pk_bf16(ps[base + 6], ps[base + 7]);
            permlane32_swap(a0, b0);
            permlane32_swap(a1, b1);
            u32x4 pw;
            pw[0] = a0; pw[1] = a1; pw[2] = b0; pw[3] = b1;
            pa[kbp] = *reinterpret_cast<bf16x8*>(&pw);
        }

        // PV: O[q][d] += P[q][key] * V[key][d]; V^T rows = d from Vs
        __builtin_amdgcn_s_setprio(1);
        #pragma unroll
        for (int jb = 0; jb < 2; ++jb) {
            const int dr = jb * 32 + q5;
            const int vsw = (dr & 7) << 4;
            #pragma unroll
            for (int kbp = 0; kbp < 4; ++kbp) {
                const bf16x8 vbf = *reinterpret_cast<const bf16x8*>(
                    VsC + dr * 128 + ((kbp * 32 + h * 16) ^ vsw));
                oacc[jb] = __builtin_amdgcn_mfma_f32_32x32x16_bf16(
                    pa[kbp], vbf, oacc[jb], 0, 0, 0);
            }
        }
        __builtin_amdgcn_s_setprio(0);

        __syncthreads();  // next buffer staged; gates overwrite
        cur ^= 1;
    }

    // epilogue: AO[b][s][h*64+d]; O[q = (r&3)+8(r>>2)+4h][d = jb*32+q5]
    const float invl = 1.0f / lsum;
    const int b = bh >> 4, hh = bh & 15;
    #pragma unroll
    for (int r = 0; r < 16; ++r) {
        const int qq = (r & 3) + 8 * (r >> 2) + 4 * h;
        const float iv = __shfl(invl, qq, 64);
        const int s = qt * 128 + w * 32 + qq;
        __bf16* orow = AO + ((size_t)(b * SEQ + s)) * DM + hh * DKH;
        orow[q5]      = (__bf16)(oacc[0][r] * iv);
        orow[32 + q5] = (__bf16)(oacc[1][r] * iv);
    }
#undef STAGE
}

extern "C" void kernel_launch(void* const* d_in, const int* in_sizes, int n_in,
                              void* d_out, int out_size, void* d_ws, size_t ws_size,
                              hipStream_t stream)
{
    const float* q  = (const float*)d_in[0];
    const float* k  = (const float*)d_in[1];
    const float* v  = (const float*)d_in[2];
    const float* Wq = (const float*)d_in[3];
    const float* bq = (const float*)d_in[4];
    const float* Wk = (const float*)d_in[5];
    const float* bk = (const float*)d_in[6];
    const float* Wv = (const float*)d_in[7];
    const float* bv = (const float*)d_in[8];
    const float* Wo = (const float*)d_in[9];
    const float* bo = (const float*)d_in[10];
    float* out = (float*)d_out;

    const size_t NQ = (size_t)NB * SEQ * DM;  // 8,388,608
    const size_t NW = (size_t)DM * DM;        // 1,048,576

    __bf16* qb  = (__bf16*)d_ws;
    __bf16* kb  = qb + NQ;
    __bf16* vb  = kb + NQ;
    __bf16* Wqb = vb + NQ;
    __bf16* Wkb = Wqb + NW;
    __bf16* Wvb = Wkb + NW;
    __bf16* Wob = Wvb + NW;
    __bf16* Qp  = Wob + NW;
    __bf16* Kp  = Qp + NQ;
    __bf16* Vp  = Kp + NQ;
    __bf16* VtG = qb;  // alias: qb dead after Q-projection
    __bf16* AO  = kb;  // alias: kb dead after K-projection

    cvt_qkv<<<dim3(4096, 3), 256, 0, stream>>>(q, k, v, qb, kb, vb);
    cvt_w<<<dim3(512, 4), 256, 0, stream>>>(Wq, Wk, Wv, Wo, Wqb, Wkb, Wvb, Wob);

    gemm_qkv<<<dim3(64, 8, 3), 256, 0, stream>>>(qb, kb, vb, Wqb, Wkb, Wvb,
                                                 bq, bk, bv, Qp, Kp, Vp);
    transpose_v<<<dim3(32, 64), 256, 0, stream>>>(Vp, VtG);
    attn_mfma<<<dim3(16, 64), 256, 0, stream>>>(Qp, Kp, VtG, AO);
    gemm_out<<<dim3(64, 8), 256, 0, stream>>>(AO, Wob, bo, out);
}